// Round 9
// baseline (47.394 us; speedup 1.0000x reference)
//
#include <hip/hip_runtime.h>
#include <hip/hip_fp16.h>

#define D_DIM 4096
#define H_DIM 4096
#define HB 16                 // rows (h) per block; 64B v-line granularity per block
#define BLK 1024              // 16 waves; wave wv owns row h0+wv
#define NBLK (H_DIM / HB)     // 256 blocks = 1 per CU
#define TILE 512              // scan tile: 8 floats per lane

__device__ __forceinline__ float fast_sigmoid(float a) {
    return __builtin_amdgcn_rcpf(1.0f + __expf(-a));
}

__device__ __forceinline__ float2 h2_to_f2(unsigned u) {
    union { unsigned u; __half2 h; } cvt;
    cvt.u = u;
    return __half22float2(cvt.h);
}

// Phase 1: wave loads its ENTIRE 16KB w-row as 16 float4 (64 VGPR), pinned
// live via empty asm on scalar components -> all 16 loads issued before one
// drain (forced MLP). Phase 2: 16 v float4 + 16 S uint2 pinned the same way.
template <bool ATOMIC>
__global__ __launch_bounds__(BLK, 4) void nade_main_kernel(
    const float* __restrict__ x,
    const float* __restrict__ w,
    const float* __restrict__ v,
    const float* __restrict__ c,
    float* __restrict__ part)
{
    __shared__ __half S[HB][D_DIM];   // 16 x 4096 fp16 = 128 KB

    const int tid  = threadIdx.x;
    const int wv   = tid >> 6;
    const int lane = tid & 63;
    const int h0   = blockIdx.x * HB;

    // ---------------- Phase 1: scan, full-row regs ----------------
    const float* wrow = w + (size_t)(h0 + wv) * D_DIM + 8 * lane;
    float carry = c[h0 + wv];

#define WLD(t) \
    float4 W##t##a = *reinterpret_cast<const float4*>(wrow + (t) * TILE); \
    float4 W##t##b = *reinterpret_cast<const float4*>(wrow + (t) * TILE + 4);
    WLD(0) WLD(1) WLD(2) WLD(3) WLD(4) WLD(5) WLD(6) WLD(7)
#undef WLD
    // pin all 16 w float4 live (scalar components; x+w pins the whole dwordx4)
    asm volatile("" :: "v"(W0a.x), "v"(W0a.w), "v"(W0b.x), "v"(W0b.w),
                       "v"(W1a.x), "v"(W1a.w), "v"(W1b.x), "v"(W1b.w),
                       "v"(W2a.x), "v"(W2a.w), "v"(W2b.x), "v"(W2b.w),
                       "v"(W3a.x), "v"(W3a.w), "v"(W3b.x), "v"(W3b.w));
    asm volatile("" :: "v"(W4a.x), "v"(W4a.w), "v"(W4b.x), "v"(W4b.w),
                       "v"(W5a.x), "v"(W5a.w), "v"(W5b.x), "v"(W5b.w),
                       "v"(W6a.x), "v"(W6a.w), "v"(W6b.x), "v"(W6b.w),
                       "v"(W7a.x), "v"(W7a.w), "v"(W7b.x), "v"(W7b.w));
    __builtin_amdgcn_sched_barrier(0);

    float4 xa0 = *reinterpret_cast<const float4*>(x + 8 * lane);
    float4 xa1 = *reinterpret_cast<const float4*>(x + 8 * lane + 4);

#define SCAN_TILE(t, w0, w1)                                                  \
    {                                                                         \
        float4 xb0, xb1;                                                      \
        if ((t) < 7) {                                                        \
            xb0 = *reinterpret_cast<const float4*>(x + ((t)+1) * TILE + 8 * lane);     \
            xb1 = *reinterpret_cast<const float4*>(x + ((t)+1) * TILE + 8 * lane + 4); \
        }                                                                     \
        float p0 = w0.x * xa0.x, p1 = w0.y * xa0.y, p2 = w0.z * xa0.z, p3 = w0.w * xa0.w; \
        float p4 = w1.x * xa1.x, p5 = w1.y * xa1.y, p6 = w1.z * xa1.z, p7 = w1.w * xa1.w; \
        float s8 = ((p0 + p1) + (p2 + p3)) + ((p4 + p5) + (p6 + p7));         \
        float incl = s8;                                                      \
        _Pragma("unroll")                                                     \
        for (int off = 1; off < 64; off <<= 1) {                              \
            float tv = __shfl_up(incl, off, 64);                              \
            incl += (lane >= off) ? tv : 0.0f;                                \
        }                                                                     \
        float tot = __shfl(incl, 63, 64);                                     \
        float a = carry + incl - s8;                                          \
        float sg0 = fast_sigmoid(a); a += p0;                                 \
        float sg1 = fast_sigmoid(a); a += p1;                                 \
        float sg2 = fast_sigmoid(a); a += p2;                                 \
        float sg3 = fast_sigmoid(a); a += p3;                                 \
        float sg4 = fast_sigmoid(a); a += p4;                                 \
        float sg5 = fast_sigmoid(a); a += p5;                                 \
        float sg6 = fast_sigmoid(a); a += p6;                                 \
        float sg7 = fast_sigmoid(a);                                          \
        carry += tot;                                                         \
        union { __half2 h2[4]; uint4 u; } P;                                  \
        P.h2[0] = __floats2half2_rn(sg0, sg1);                                \
        P.h2[1] = __floats2half2_rn(sg2, sg3);                                \
        P.h2[2] = __floats2half2_rn(sg4, sg5);                                \
        P.h2[3] = __floats2half2_rn(sg6, sg7);                                \
        *reinterpret_cast<uint4*>(&S[wv][(t) * TILE + 8 * lane]) = P.u;       \
        xa0 = xb0; xa1 = xb1;                                                 \
    }

    SCAN_TILE(0, W0a, W0b)
    SCAN_TILE(1, W1a, W1b)
    SCAN_TILE(2, W2a, W2b)
    SCAN_TILE(3, W3a, W3b)
    SCAN_TILE(4, W4a, W4b)
    SCAN_TILE(5, W5a, W5b)
    SCAN_TILE(6, W6a, W6b)
    SCAN_TILE(7, W7a, W7b)
#undef SCAN_TILE

    __syncthreads();   // the ONLY barrier

    // ---------------- Phase 2: reduce, MLP-forced ----------------
    const int i0 = 4 * tid;
    const float* vp0 = v + (size_t)i0 * H_DIM + h0;
    const float* vp1 = vp0 + H_DIM;
    const float* vp2 = vp0 + 2 * (size_t)H_DIM;
    const float* vp3 = vp0 + 3 * (size_t)H_DIM;

#define LD4(p, o) (*reinterpret_cast<const float4*>((p) + (o)))
    float4 va0 = LD4(vp0, 0), va1 = LD4(vp0, 4), va2 = LD4(vp0, 8),  va3 = LD4(vp0, 12);
    float4 vb0 = LD4(vp1, 0), vb1 = LD4(vp1, 4), vb2 = LD4(vp1, 8),  vb3 = LD4(vp1, 12);
    float4 vc0 = LD4(vp2, 0), vc1 = LD4(vp2, 4), vc2 = LD4(vp2, 8),  vc3 = LD4(vp2, 12);
    float4 vd0 = LD4(vp3, 0), vd1 = LD4(vp3, 4), vd2 = LD4(vp3, 8),  vd3 = LD4(vp3, 12);
#undef LD4
#define LDS2(h) (*reinterpret_cast<const uint2*>(&S[h][i0]))
    uint2 s0 = LDS2(0),  s1 = LDS2(1),  s2 = LDS2(2),  s3 = LDS2(3);
    uint2 s4 = LDS2(4),  s5 = LDS2(5),  s6 = LDS2(6),  s7 = LDS2(7);
    uint2 s8 = LDS2(8),  s9 = LDS2(9),  s10 = LDS2(10), s11 = LDS2(11);
    uint2 s12 = LDS2(12), s13 = LDS2(13), s14 = LDS2(14), s15 = LDS2(15);
#undef LDS2
    // pin all global + LDS reads live (scalar components)
    asm volatile("" :: "v"(va0.x), "v"(va0.w), "v"(va1.x), "v"(va1.w),
                       "v"(va2.x), "v"(va2.w), "v"(va3.x), "v"(va3.w),
                       "v"(vb0.x), "v"(vb0.w), "v"(vb1.x), "v"(vb1.w),
                       "v"(vb2.x), "v"(vb2.w), "v"(vb3.x), "v"(vb3.w));
    asm volatile("" :: "v"(vc0.x), "v"(vc0.w), "v"(vc1.x), "v"(vc1.w),
                       "v"(vc2.x), "v"(vc2.w), "v"(vc3.x), "v"(vc3.w),
                       "v"(vd0.x), "v"(vd0.w), "v"(vd1.x), "v"(vd1.w),
                       "v"(vd2.x), "v"(vd2.w), "v"(vd3.x), "v"(vd3.w));
    asm volatile("" :: "v"(s0.x),  "v"(s0.y),  "v"(s1.x),  "v"(s1.y),
                       "v"(s2.x),  "v"(s2.y),  "v"(s3.x),  "v"(s3.y),
                       "v"(s4.x),  "v"(s4.y),  "v"(s5.x),  "v"(s5.y),
                       "v"(s6.x),  "v"(s6.y),  "v"(s7.x),  "v"(s7.y));
    asm volatile("" :: "v"(s8.x),  "v"(s8.y),  "v"(s9.x),  "v"(s9.y),
                       "v"(s10.x), "v"(s10.y), "v"(s11.x), "v"(s11.y),
                       "v"(s12.x), "v"(s12.y), "v"(s13.x), "v"(s13.y),
                       "v"(s14.x), "v"(s14.y), "v"(s15.x), "v"(s15.y));
    __builtin_amdgcn_sched_barrier(0);

    float acc0 = 0.0f, acc1 = 0.0f, acc2 = 0.0f, acc3 = 0.0f;
#define ACC4(vq, h2a, h2b, h2c, h2d)                                   \
    {                                                                   \
        float2 f0 = h2_to_f2(h2a), f1 = h2_to_f2(h2b);                 \
        float2 f2 = h2_to_f2(h2c), f3 = h2_to_f2(h2d);                 \
        accX += vq.x * f0.FLD + vq.y * f1.FLD + vq.z * f2.FLD + vq.w * f3.FLD; \
    }
#define accX acc0
#define FLD x
    ACC4(va0, s0.x,  s1.x,  s2.x,  s3.x)
    ACC4(va1, s4.x,  s5.x,  s6.x,  s7.x)
    ACC4(va2, s8.x,  s9.x,  s10.x, s11.x)
    ACC4(va3, s12.x, s13.x, s14.x, s15.x)
#undef FLD
#undef accX
#define accX acc1
#define FLD y
    ACC4(vb0, s0.x,  s1.x,  s2.x,  s3.x)
    ACC4(vb1, s4.x,  s5.x,  s6.x,  s7.x)
    ACC4(vb2, s8.x,  s9.x,  s10.x, s11.x)
    ACC4(vb3, s12.x, s13.x, s14.x, s15.x)
#undef FLD
#undef accX
#define accX acc2
#define FLD x
    ACC4(vc0, s0.y,  s1.y,  s2.y,  s3.y)
    ACC4(vc1, s4.y,  s5.y,  s6.y,  s7.y)
    ACC4(vc2, s8.y,  s9.y,  s10.y, s11.y)
    ACC4(vc3, s12.y, s13.y, s14.y, s15.y)
#undef FLD
#undef accX
#define accX acc3
#define FLD y
    ACC4(vd0, s0.y,  s1.y,  s2.y,  s3.y)
    ACC4(vd1, s4.y,  s5.y,  s6.y,  s7.y)
    ACC4(vd2, s8.y,  s9.y,  s10.y, s11.y)
    ACC4(vd3, s12.y, s13.y, s14.y, s15.y)
#undef FLD
#undef accX
#undef ACC4

    if (ATOMIC) {
        atomicAdd(&part[i0 + 0], acc0);
        atomicAdd(&part[i0 + 1], acc1);
        atomicAdd(&part[i0 + 2], acc2);
        atomicAdd(&part[i0 + 3], acc3);
    } else {
        float4 o; o.x = acc0; o.y = acc1; o.z = acc2; o.w = acc3;
        *reinterpret_cast<float4*>(part + (size_t)blockIdx.x * D_DIM + i0) = o;
    }
}

// Grid: D/64 blocks x 1024 threads. Sums the [NBLK][D] partial matrix (coalesced).
__global__ __launch_bounds__(1024, 1) void nade_reduce_kernel(
    const float* __restrict__ part,
    const float* __restrict__ b,
    float* __restrict__ out)
{
    __shared__ float red[16][64];
    const int tid = threadIdx.x;
    const int bg  = tid >> 6;      // wave id 0..15
    const int il  = tid & 63;
    const int i   = blockIdx.x * 64 + il;
    float s = 0.0f;
    #pragma unroll
    for (int j = 0; j < NBLK / 16; ++j)
        s += part[(size_t)(bg * (NBLK / 16) + j) * D_DIM + i];
    red[bg][il] = s;
    __syncthreads();
    if (tid < 64) {
        float t = b[blockIdx.x * 64 + tid];
        #pragma unroll
        for (int j = 0; j < 16; ++j) t += red[j][tid];
        out[blockIdx.x * 64 + tid] = fast_sigmoid(t);
    }
}

__global__ __launch_bounds__(256, 1) void nade_final_atomic(
    const float* __restrict__ logits,
    const float* __restrict__ b,
    float* __restrict__ out)
{
    const int i = blockIdx.x * 256 + threadIdx.x;
    out[i] = fast_sigmoid(logits[i] + b[i]);
}

extern "C" void kernel_launch(void* const* d_in, const int* in_sizes, int n_in,
                              void* d_out, int out_size, void* d_ws, size_t ws_size,
                              hipStream_t stream)
{
    const float* x = (const float*)d_in[0];
    const float* w = (const float*)d_in[1];
    const float* b = (const float*)d_in[2];
    const float* v = (const float*)d_in[3];
    const float* c = (const float*)d_in[4];
    float* out = (float*)d_out;
    float* ws  = (float*)d_ws;

    const size_t need = (size_t)NBLK * D_DIM * sizeof(float);
    if (ws_size >= need) {
        nade_main_kernel<false><<<NBLK, BLK, 0, stream>>>(x, w, v, c, ws);
        nade_reduce_kernel<<<D_DIM / 64, 1024, 0, stream>>>(ws, b, out);
    } else {
        hipMemsetAsync(d_ws, 0, D_DIM * sizeof(float), stream);
        nade_main_kernel<true><<<NBLK, BLK, 0, stream>>>(x, w, v, c, ws);
        nade_final_atomic<<<D_DIM / 256, 256, 0, stream>>>(ws, b, out);
    }
}

// Round 10
// 45.727 us; speedup vs baseline: 1.0364x; 1.0364x over previous
//
#include <hip/hip_runtime.h>
#include <hip/hip_fp16.h>

#define D_DIM 4096
#define H_DIM 4096

__device__ __forceinline__ float fast_sigmoid(float a) {
    return __builtin_amdgcn_rcpf(1.0f + __expf(-a));
}

// ---------------- Kernel A: row scans -> S fp16 (32 MB ws) ----------------
// grid 1024 x 256 thr; wave owns row h = blockIdx.x*4 + (tid>>6).
// Streams w rows (1KB+ granule), writes S rows coalesced. Copy-like kernel.
__global__ __launch_bounds__(256, 4) void nade_scan_kernel(
    const float* __restrict__ x,
    const float* __restrict__ w,
    const float* __restrict__ c,
    __half* __restrict__ S)
{
    const int tid  = threadIdx.x;
    const int lane = tid & 63;
    const int h    = blockIdx.x * 4 + (tid >> 6);

    const float* wrow = w + (size_t)h * D_DIM + 8 * lane;
    __half*      srow = S + (size_t)h * D_DIM + 8 * lane;
    float carry = c[h];

    float4 wc0 = *reinterpret_cast<const float4*>(wrow);
    float4 wc1 = *reinterpret_cast<const float4*>(wrow + 4);

    #pragma unroll
    for (int t = 0; t < 8; ++t) {
        float4 wn0, wn1;
        if (t < 7) {
            wn0 = *reinterpret_cast<const float4*>(wrow + (t + 1) * 512);
            wn1 = *reinterpret_cast<const float4*>(wrow + (t + 1) * 512 + 4);
        }
        float4 x0 = *reinterpret_cast<const float4*>(x + t * 512 + 8 * lane);
        float4 x1 = *reinterpret_cast<const float4*>(x + t * 512 + 8 * lane + 4);

        float p0 = wc0.x * x0.x, p1 = wc0.y * x0.y, p2 = wc0.z * x0.z, p3 = wc0.w * x0.w;
        float p4 = wc1.x * x1.x, p5 = wc1.y * x1.y, p6 = wc1.z * x1.z, p7 = wc1.w * x1.w;
        float s8 = ((p0 + p1) + (p2 + p3)) + ((p4 + p5) + (p6 + p7));
        float incl = s8;
        #pragma unroll
        for (int off = 1; off < 64; off <<= 1) {
            float tv = __shfl_up(incl, off, 64);
            incl += (lane >= off) ? tv : 0.0f;
        }
        float tot = __shfl(incl, 63, 64);
        float a = carry + incl - s8;          // exclusive prefix + carry
        float sg0 = fast_sigmoid(a); a += p0;
        float sg1 = fast_sigmoid(a); a += p1;
        float sg2 = fast_sigmoid(a); a += p2;
        float sg3 = fast_sigmoid(a); a += p3;
        float sg4 = fast_sigmoid(a); a += p4;
        float sg5 = fast_sigmoid(a); a += p5;
        float sg6 = fast_sigmoid(a); a += p6;
        float sg7 = fast_sigmoid(a);
        carry += tot;

        union { __half2 h2[4]; uint4 u; } P;
        P.h2[0] = __floats2half2_rn(sg0, sg1);
        P.h2[1] = __floats2half2_rn(sg2, sg3);
        P.h2[2] = __floats2half2_rn(sg4, sg5);
        P.h2[3] = __floats2half2_rn(sg6, sg7);
        *reinterpret_cast<uint4*>(srow + t * 512) = P.u;

        wc0 = wn0; wc1 = wn1;
    }
}

// ---------------- Kernel B: part[ht][i] = sum_{h in tile} v[i,h]*S[h,i] ----
// grid 2048 (64 i-tiles x 32 h-tiles) x 256 thr = 8 blocks/CU = 32 waves/CU.
// v: 128B/thread, 512B/row/block. S: 128B row slices staged in 16KB LDS.
__global__ __launch_bounds__(256, 8) void nade_vdot_kernel(
    const float* __restrict__ v,
    const __half* __restrict__ S,
    float* __restrict__ part)
{
    __shared__ __half Sl[128][64];   // 16 KB
    __shared__ float red[4][64];

    const int tid = threadIdx.x;
    const int it  = blockIdx.x & 63;
    const int ht  = blockIdx.x >> 6;
    const int i0  = it * 64;
    const int h0  = ht * 128;

    // stage S tile: 128 rows x 128B; thread loads one uint4 per pass
    {
        const int r  = tid >> 3;       // 32 rows per pass
        const int c8 = tid & 7;        // 16B chunk in row
        #pragma unroll
        for (int p = 0; p < 4; ++p) {
            const int hh = p * 32 + r;
            uint4 d = *reinterpret_cast<const uint4*>(
                S + (size_t)(h0 + hh) * D_DIM + i0 + c8 * 8);
            *reinterpret_cast<uint4*>(&Sl[hh][c8 * 8]) = d;
        }
    }
    __syncthreads();

    const int il = tid & 63;           // i within tile (lane)
    const int q  = tid >> 6;           // wave = 32-h subrange
    const float* vp = v + (size_t)(i0 + il) * H_DIM + h0 + q * 32;

    float4 va[8];
    #pragma unroll
    for (int k = 0; k < 8; ++k)
        va[k] = *reinterpret_cast<const float4*>(vp + 4 * k);

    float acc = 0.0f;
    #pragma unroll
    for (int k = 0; k < 8; ++k) {
        const int hb = q * 32 + 4 * k;
        acc += va[k].x * __half2float(Sl[hb + 0][il])
             + va[k].y * __half2float(Sl[hb + 1][il])
             + va[k].z * __half2float(Sl[hb + 2][il])
             + va[k].w * __half2float(Sl[hb + 3][il]);
    }
    red[q][il] = acc;
    __syncthreads();
    if (q == 0)
        part[(size_t)ht * D_DIM + i0 + il] =
            red[0][il] + red[1][il] + red[2][il] + red[3][il];
}

// ---------------- Kernel C: out = sigmoid(b + sum_32 part) ----------------
__global__ __launch_bounds__(256, 8) void nade_out_kernel(
    const float* __restrict__ part,
    const float* __restrict__ b,
    float* __restrict__ out)
{
    const int i = blockIdx.x * 256 + threadIdx.x;
    float t = b[i];
    #pragma unroll
    for (int s = 0; s < 32; ++s)
        t += part[(size_t)s * D_DIM + i];
    out[i] = fast_sigmoid(t);
}

// ---------------- Fallback (ws too small): fused atomic, R5 structure -----
__global__ __launch_bounds__(1024, 1) void nade_fused_atomic(
    const float* __restrict__ x,
    const float* __restrict__ w,
    const float* __restrict__ v,
    const float* __restrict__ c,
    float* __restrict__ logits)
{
    __shared__ __half S[16][D_DIM];   // 128 KB

    const int tid  = threadIdx.x;
    const int wv   = tid >> 6;
    const int lane = tid & 63;
    const int h0   = blockIdx.x * 16;

    const float* wrow = w + (size_t)(h0 + wv) * D_DIM + 8 * lane;
    float carry = c[h0 + wv];
    #pragma unroll
    for (int t = 0; t < 8; ++t) {
        float4 w0 = *reinterpret_cast<const float4*>(wrow + t * 512);
        float4 w1 = *reinterpret_cast<const float4*>(wrow + t * 512 + 4);
        float4 x0 = *reinterpret_cast<const float4*>(x + t * 512 + 8 * lane);
        float4 x1 = *reinterpret_cast<const float4*>(x + t * 512 + 8 * lane + 4);
        float p0 = w0.x * x0.x, p1 = w0.y * x0.y, p2 = w0.z * x0.z, p3 = w0.w * x0.w;
        float p4 = w1.x * x1.x, p5 = w1.y * x1.y, p6 = w1.z * x1.z, p7 = w1.w * x1.w;
        float s8 = ((p0 + p1) + (p2 + p3)) + ((p4 + p5) + (p6 + p7));
        float incl = s8;
        #pragma unroll
        for (int off = 1; off < 64; off <<= 1) {
            float tv = __shfl_up(incl, off, 64);
            incl += (lane >= off) ? tv : 0.0f;
        }
        float tot = __shfl(incl, 63, 64);
        float a = carry + incl - s8;
        float sg0 = fast_sigmoid(a); a += p0;
        float sg1 = fast_sigmoid(a); a += p1;
        float sg2 = fast_sigmoid(a); a += p2;
        float sg3 = fast_sigmoid(a); a += p3;
        float sg4 = fast_sigmoid(a); a += p4;
        float sg5 = fast_sigmoid(a); a += p5;
        float sg6 = fast_sigmoid(a); a += p6;
        float sg7 = fast_sigmoid(a);
        carry += tot;
        union { __half2 h2[4]; uint4 u; } P;
        P.h2[0] = __floats2half2_rn(sg0, sg1);
        P.h2[1] = __floats2half2_rn(sg2, sg3);
        P.h2[2] = __floats2half2_rn(sg4, sg5);
        P.h2[3] = __floats2half2_rn(sg6, sg7);
        *reinterpret_cast<uint4*>(&S[wv][t * 512 + 8 * lane]) = P.u;
    }
    __syncthreads();

    const int i0 = 4 * tid;
    float acc[4] = {0.f, 0.f, 0.f, 0.f};
    #pragma unroll
    for (int r = 0; r < 4; ++r) {
        const float* vp = v + (size_t)(i0 + r) * H_DIM + h0;
        float4 q0 = *reinterpret_cast<const float4*>(vp);
        float4 q1 = *reinterpret_cast<const float4*>(vp + 4);
        float4 q2 = *reinterpret_cast<const float4*>(vp + 8);
        float4 q3 = *reinterpret_cast<const float4*>(vp + 12);
        acc[r] = q0.x * __half2float(S[0][i0 + r])  + q0.y * __half2float(S[1][i0 + r])
               + q0.z * __half2float(S[2][i0 + r])  + q0.w * __half2float(S[3][i0 + r])
               + q1.x * __half2float(S[4][i0 + r])  + q1.y * __half2float(S[5][i0 + r])
               + q1.z * __half2float(S[6][i0 + r])  + q1.w * __half2float(S[7][i0 + r])
               + q2.x * __half2float(S[8][i0 + r])  + q2.y * __half2float(S[9][i0 + r])
               + q2.z * __half2float(S[10][i0 + r]) + q2.w * __half2float(S[11][i0 + r])
               + q3.x * __half2float(S[12][i0 + r]) + q3.y * __half2float(S[13][i0 + r])
               + q3.z * __half2float(S[14][i0 + r]) + q3.w * __half2float(S[15][i0 + r]);
    }
    #pragma unroll
    for (int r = 0; r < 4; ++r) atomicAdd(&logits[i0 + r], acc[r]);
}

__global__ __launch_bounds__(256, 1) void nade_final_atomic(
    const float* __restrict__ logits,
    const float* __restrict__ b,
    float* __restrict__ out)
{
    const int i = blockIdx.x * 256 + threadIdx.x;
    out[i] = fast_sigmoid(logits[i] + b[i]);
}

extern "C" void kernel_launch(void* const* d_in, const int* in_sizes, int n_in,
                              void* d_out, int out_size, void* d_ws, size_t ws_size,
                              hipStream_t stream)
{
    const float* x = (const float*)d_in[0];
    const float* w = (const float*)d_in[1];
    const float* b = (const float*)d_in[2];
    const float* v = (const float*)d_in[3];
    const float* c = (const float*)d_in[4];
    float* out = (float*)d_out;

    const size_t s_bytes    = (size_t)H_DIM * D_DIM * sizeof(__half);   // 32 MB
    const size_t part_bytes = (size_t)32 * D_DIM * sizeof(float);       // 512 KB

    if (ws_size >= s_bytes + part_bytes) {
        __half* S    = (__half*)d_ws;
        float*  part = (float*)((char*)d_ws + s_bytes);
        nade_scan_kernel<<<H_DIM / 4, 256, 0, stream>>>(x, w, c, S);
        nade_vdot_kernel<<<64 * 32, 256, 0, stream>>>(v, S, part);
        nade_out_kernel<<<D_DIM / 256, 256, 0, stream>>>(part, b, out);
    } else {
        float* logits = (float*)d_ws;
        hipMemsetAsync(logits, 0, D_DIM * sizeof(float), stream);
        nade_fused_atomic<<<H_DIM / 16, 1024, 0, stream>>>(x, w, v, c, logits);
        nade_final_atomic<<<D_DIM / 256, 256, 0, stream>>>(logits, b, out);
    }
}